// Round 7
// baseline (710.926 us; speedup 1.0000x reference)
//
#include <hip/hip_runtime.h>
#include <hip/hip_bf16.h>

#define B_  2
#define T_  2048
#define H_  2048
#define NH_ 16
#define HD_ 128

typedef __attribute__((ext_vector_type(8))) short  short8;   // 8 bf16 in 4 VGPRs
typedef __attribute__((ext_vector_type(4))) float  floatx4;  // MFMA C/D

__device__ __forceinline__ unsigned short f2bf(float x) {
    union { float f; unsigned int u; } c; c.f = x;
    unsigned int r = c.u + 0x7FFF + ((c.u >> 16) & 1);   // RNE
    return (unsigned short)(r >> 16);
}
__device__ __forceinline__ float bf2f(unsigned short u) {
    union { float f; unsigned int i; } c;
    c.i = ((unsigned int)u) << 16;
    return c.f;
}

__device__ __forceinline__ void gload_lds16(const void* g, void* l) {
    __builtin_amdgcn_global_load_lds(
        (__attribute__((address_space(1))) void*)g,
        (__attribute__((address_space(3))) void*)l, 16, 0, 0);
}

// ---------------- fused fp32 -> bf16 convert: 6 equal chunks of WN elems ---------
__global__ __launch_bounds__(256) void f32_to_bf16_multi(
    const float* __restrict__ s0, const float* __restrict__ s1,
    const float* __restrict__ s2, const float* __restrict__ s3,
    const float* __restrict__ s4, const float* __restrict__ s5,
    unsigned short* __restrict__ d0, unsigned short* __restrict__ d1,
    unsigned short* __restrict__ d2, unsigned short* __restrict__ d3,
    unsigned short* __restrict__ d4, unsigned short* __restrict__ d5)
{
    const float* s; unsigned short* d;
    switch (blockIdx.y) {
        case 0: s = s0; d = d0; break;
        case 1: s = s1; d = d1; break;
        case 2: s = s2; d = d2; break;
        case 3: s = s3; d = d3; break;
        case 4: s = s4; d = d4; break;
        default: s = s5; d = d5; break;
    }
    const int i = (blockIdx.x * 256 + threadIdx.x) * 4;
    float4 v = *(const float4*)(s + i);
    ushort4 o;
    o.x = f2bf(v.x); o.y = f2bf(v.y); o.z = f2bf(v.z); o.w = f2bf(v.w);
    *(ushort4*)(d + i) = o;
}

// ---------------- bf16 MFMA GEMM (round-6 verified, unchanged) -------------------
template<bool BF16_OUT>
__global__ __launch_bounds__(256) void gemm_mfma(
    const unsigned short* __restrict__ A,   // [M,K] bf16
    const unsigned short* __restrict__ W,   // [N,K] bf16
    float* __restrict__ Yf, unsigned short* __restrict__ Yb,
    int M, int N, int K)
{
    __shared__ __attribute__((aligned(16))) unsigned short Ah[128 * 32];
    __shared__ __attribute__((aligned(16))) unsigned short Bh[128 * 32];

    const int tid  = threadIdx.x;
    const int lane = tid & 63;
    const int n16  = lane & 15;
    const int quad = lane >> 4;
    const int w    = tid >> 6;
    const int wm   = w & 1, wn = w >> 1;

    const int m0 = blockIdx.y * 128;
    const int n0 = blockIdx.x * 128;

    const int srow = tid >> 2;
    const int scol = (tid & 3) * 8;

    floatx4 acc[4][4];
    #pragma unroll
    for (int i = 0; i < 4; i++)
        #pragma unroll
        for (int j = 0; j < 4; j++) acc[i][j] = (floatx4){0.f, 0.f, 0.f, 0.f};

    for (int k0 = 0; k0 < K; k0 += 32) {
        __syncthreads();
        gload_lds16(A + (size_t)(m0 +      srow) * K + k0 + scol, Ah + (size_t)tid * 8);
        gload_lds16(A + (size_t)(m0 + 64 + srow) * K + k0 + scol, Ah + (size_t)(tid + 256) * 8);
        gload_lds16(W + (size_t)(n0 +      srow) * K + k0 + scol, Bh + (size_t)tid * 8);
        gload_lds16(W + (size_t)(n0 + 64 + srow) * K + k0 + scol, Bh + (size_t)(tid + 256) * 8);
        __syncthreads();

        short8 af[4], bfr[4];
        #pragma unroll
        for (int i = 0; i < 4; i++) {
            af[i]  = *(const short8*)(Ah + (wm * 64 + i * 16 + n16) * 32 + quad * 8);
            bfr[i] = *(const short8*)(Bh + (wn * 64 + i * 16 + n16) * 32 + quad * 8);
        }
        #pragma unroll
        for (int i = 0; i < 4; i++)
            #pragma unroll
            for (int j = 0; j < 4; j++)
                acc[i][j] = __builtin_amdgcn_mfma_f32_16x16x32_bf16(af[i], bfr[j], acc[i][j], 0, 0, 0);
    }

    #pragma unroll
    for (int i = 0; i < 4; i++) {
        const int rbase = m0 + wm * 64 + i * 16 + quad * 4;
        #pragma unroll
        for (int r = 0; r < 4; r++) {
            const size_t row = rbase + r;
            #pragma unroll
            for (int j = 0; j < 4; j++) {
                const size_t col = n0 + wn * 64 + j * 16 + n16;
                if (BF16_OUT) Yb[row * N + col] = f2bf(acc[i][j][r]);
                else          Yf[row * N + col] = acc[i][j][r];
            }
        }
    }
}

// ---------------- RoPE: bf16 [B,T,H] -> bf16 [BH][T][HD] (q scaled) --------------
__global__ __launch_bounds__(256) void rope_convert_qk(
    const unsigned short* __restrict__ qp, const unsigned short* __restrict__ kp,
    const float* __restrict__ cosp, const float* __restrict__ sinp,
    unsigned short* __restrict__ qh, unsigned short* __restrict__ kh)
{
    const int idx  = blockIdx.x * 256 + threadIdx.x;
    const int d    = idx & 63;
    const int rest = idx >> 6;
    const int h    = rest & 15;
    const int bt   = rest >> 4;
    const int t    = bt & (T_ - 1);
    const int b    = bt >> 11;
    const size_t ibase = (size_t)bt * H_ + h * HD_;
    const size_t obase = (((size_t)b * NH_ + h) * T_ + t) * HD_;

    const float c0 = cosp[t*HD_ + d],      s0 = sinp[t*HD_ + d];
    const float c1 = cosp[t*HD_ + d + 64], s1 = sinp[t*HD_ + d + 64];
    const float sc = 0.08838834764831845f;

    float q0 = bf2f(qp[ibase + d]), q1 = bf2f(qp[ibase + d + 64]);
    qh[obase + d]      = f2bf((q0*c0 - q1*s0) * sc);
    qh[obase + d + 64] = f2bf((q1*c1 + q0*s1) * sc);

    float k0 = bf2f(kp[ibase + d]), k1 = bf2f(kp[ibase + d + 64]);
    kh[obase + d]      = f2bf(k0*c0 - k1*s0);
    kh[obase + d + 64] = f2bf(k1*c1 + k0*s1);
}

// ---------------- V transpose: bf16 [B,T,H] -> bf16 [BH][HD][T] ------------------
__global__ __launch_bounds__(256) void transpose_v(
    const unsigned short* __restrict__ vb, unsigned short* __restrict__ vh)
{
    __shared__ float tile[64][65];
    const int t0 = blockIdx.x * 64;
    const int d0 = blockIdx.y * 64;
    const int bh = blockIdx.z;
    const int b  = bh >> 4, h = bh & 15;

    for (int i = threadIdx.x; i < 4096; i += 256) {
        int r = i >> 6, c = i & 63;
        tile[r][c] = bf2f(vb[((size_t)b*T_ + t0 + r) * H_ + h*HD_ + d0 + c]);
    }
    __syncthreads();
    for (int i = threadIdx.x; i < 4096; i += 256) {
        int dr = i >> 6, tc = i & 63;
        vh[((size_t)bh * HD_ + d0 + dr) * T_ + t0 + tc] = f2bf(tile[tc][dr]);
    }
}

// ---------------- MFMA flash attention, 128 q-rows/block -------------------------
// 4 waves; wave w owns row-tiles rt=0,1 at rows qb*128 + rt*64 + w*16 (+0..15).
// KV tiles of 64 keys in LDS. Balanced causal schedule via qb remap.
#define LDS_KROW 136
#define LDS_VROW 72
#define LDS_PROW 72

__global__ __launch_bounds__(256) void attn_mfma(
    const unsigned short* __restrict__ qh,   // [BH][T][HD] (pre-scaled)
    const unsigned short* __restrict__ kh,   // [BH][T][HD]
    const unsigned short* __restrict__ vh,   // [BH][HD][T]
    unsigned short* __restrict__ o)          // [B][T][H] bf16
{
    __shared__ __attribute__((aligned(16))) unsigned short Ks[64 * LDS_KROW];
    __shared__ __attribute__((aligned(16))) unsigned short Vs[128 * LDS_VROW];
    __shared__ __attribute__((aligned(16))) unsigned short Ps[4][16 * LDS_PROW];

    const int tid  = threadIdx.x;
    const int lane = tid & 63;
    const int w    = tid >> 6;
    const int n16  = lane & 15;
    const int quad = lane >> 4;
    const int bh   = blockIdx.y;
    const int xx   = blockIdx.x;                       // 0..15
    const int qb   = (xx & 1) ? (15 - (xx >> 1)) : (xx >> 1);  // balanced pairing

    short8 qf[2][4];
    #pragma unroll
    for (int rt = 0; rt < 2; rt++) {
        const size_t qbase = ((size_t)bh * T_ + qb*128 + rt*64 + w*16 + n16) * HD_ + quad * 8;
        #pragma unroll
        for (int c = 0; c < 4; c++)
            qf[rt][c] = *(const short8*)(qh + qbase + c * 32);
    }

    floatx4 of[2][8];
    float mrow[2][4], lrow[2][4];
    #pragma unroll
    for (int rt = 0; rt < 2; rt++) {
        #pragma unroll
        for (int i = 0; i < 8; i++) of[rt][i] = (floatx4){0.f, 0.f, 0.f, 0.f};
        #pragma unroll
        for (int r = 0; r < 4; r++) { mrow[rt][r] = -INFINITY; lrow[rt][r] = 0.f; }
    }

    const int nkv = 2 * qb + 2;
    for (int kv = 0; kv < nkv; kv++) {
        const int kv0 = kv * 64;
        __syncthreads();
        {
            const size_t gk = ((size_t)bh * T_ + kv0) * HD_;
            #pragma unroll
            for (int it = 0; it < 4; it++) {
                int i = tid + it * 256;
                int row = i >> 4, c8 = (i & 15) * 8;
                *(short8*)(Ks + row * LDS_KROW + c8) =
                    *(const short8*)(kh + gk + (size_t)row * HD_ + c8);
            }
            const size_t gv = (size_t)bh * HD_ * T_ + kv0;
            #pragma unroll
            for (int it = 0; it < 4; it++) {
                int i = tid + it * 256;
                int d = i >> 3, k8 = (i & 7) * 8;
                *(short8*)(Vs + d * LDS_VROW + k8) =
                    *(const short8*)(vh + gv + (size_t)d * T_ + k8);
            }
        }
        __syncthreads();

        #pragma unroll
        for (int rt = 0; rt < 2; rt++) {
            if (rt == 0 && kv == nkv - 1) continue;    // rt0 fully masked on last tile

            floatx4 s[4];
            #pragma unroll
            for (int kg = 0; kg < 4; kg++) {
                floatx4 acc = {0.f, 0.f, 0.f, 0.f};
                #pragma unroll
                for (int c = 0; c < 4; c++) {
                    short8 kf = *(const short8*)(Ks + (kg*16 + n16) * LDS_KROW + c*32 + quad*8);
                    acc = __builtin_amdgcn_mfma_f32_16x16x32_bf16(qf[rt][c], kf, acc, 0, 0, 0);
                }
                s[kg] = acc;
            }

            float alpha[4];
            #pragma unroll
            for (int r = 0; r < 4; r++) {
                const int qrow = qb*128 + rt*64 + w*16 + quad*4 + r;
                float v0 = s[0][r], v1 = s[1][r], v2 = s[2][r], v3 = s[3][r];
                if (kv0 +  0 + n16 > qrow) v0 = -INFINITY;
                if (kv0 + 16 + n16 > qrow) v1 = -INFINITY;
                if (kv0 + 32 + n16 > qrow) v2 = -INFINITY;
                if (kv0 + 48 + n16 > qrow) v3 = -INFINITY;

                float tm = fmaxf(fmaxf(v0, v1), fmaxf(v2, v3));
                tm = fmaxf(tm, __shfl_xor(tm, 1));
                tm = fmaxf(tm, __shfl_xor(tm, 2));
                tm = fmaxf(tm, __shfl_xor(tm, 4));
                tm = fmaxf(tm, __shfl_xor(tm, 8));

                const float mnew = fmaxf(mrow[rt][r], tm);
                const float a    = __expf(mrow[rt][r] - mnew);
                const float p0 = __expf(v0 - mnew), p1 = __expf(v1 - mnew);
                const float p2 = __expf(v2 - mnew), p3 = __expf(v3 - mnew);

                float ts = p0 + p1 + p2 + p3;
                ts += __shfl_xor(ts, 1);
                ts += __shfl_xor(ts, 2);
                ts += __shfl_xor(ts, 4);
                ts += __shfl_xor(ts, 8);

                lrow[rt][r] = lrow[rt][r] * a + ts;
                mrow[rt][r] = mnew;
                alpha[r] = a;

                const int prow = (quad * 4 + r) * LDS_PROW;
                Ps[w][prow + n16 +  0] = f2bf(p0);
                Ps[w][prow + n16 + 16] = f2bf(p1);
                Ps[w][prow + n16 + 32] = f2bf(p2);
                Ps[w][prow + n16 + 48] = f2bf(p3);
            }
            #pragma unroll
            for (int nt = 0; nt < 8; nt++)
                #pragma unroll
                for (int r = 0; r < 4; r++) of[rt][nt][r] *= alpha[r];

            // wave-internal P round-trip (no barrier needed; same-wave DS ordering)
            short8 pf0 = *(const short8*)(&Ps[w][n16 * LDS_PROW + quad * 8]);
            short8 pf1 = *(const short8*)(&Ps[w][n16 * LDS_PROW + 32 + quad * 8]);
            #pragma unroll
            for (int nt = 0; nt < 8; nt++) {
                short8 vf0 = *(const short8*)(Vs + (nt*16 + n16) * LDS_VROW + quad * 8);
                short8 vf1 = *(const short8*)(Vs + (nt*16 + n16) * LDS_VROW + 32 + quad * 8);
                of[rt][nt] = __builtin_amdgcn_mfma_f32_16x16x32_bf16(pf0, vf0, of[rt][nt], 0, 0, 0);
                of[rt][nt] = __builtin_amdgcn_mfma_f32_16x16x32_bf16(pf1, vf1, of[rt][nt], 0, 0, 0);
            }
        }
    }

    const int b = bh >> 4, h = bh & 15;
    #pragma unroll
    for (int rt = 0; rt < 2; rt++)
        #pragma unroll
        for (int r = 0; r < 4; r++) {
            const float inv = 1.f / lrow[rt][r];
            const size_t orow = ((size_t)b * T_ + qb*128 + rt*64 + w*16 + quad*4 + r) * H_ + h * HD_;
            #pragma unroll
            for (int nt = 0; nt < 8; nt++)
                o[orow + nt*16 + n16] = f2bf(of[rt][nt][r] * inv);
        }
}

extern "C" void kernel_launch(void* const* d_in, const int* in_sizes, int n_in,
                              void* d_out, int out_size, void* d_ws, size_t ws_size,
                              hipStream_t stream)
{
    const float* x    = (const float*)d_in[0];
    const float* cosp = (const float*)d_in[1];
    const float* sinp = (const float*)d_in[2];
    const float* Wq   = (const float*)d_in[3];
    const float* Wk   = (const float*)d_in[4];
    const float* Wv   = (const float*)d_in[5];
    const float* Wo   = (const float*)d_in[6];

    const size_t NEL  = (size_t)B_ * T_ * H_;   // 8388608
    const size_t NB   = NEL * 4;                // 33.5 MB
    const int    WN   = H_ * H_;                // 4194304
    char* ws = (char*)d_ws;

    unsigned short* xh   = (unsigned short*)(ws);
    unsigned short* Woh  = (unsigned short*)(ws + NB/2);
    unsigned short* Wqh  = (unsigned short*)(ws + 3*NB/4);
    unsigned short* Wkh  = (unsigned short*)(ws + NB);
    unsigned short* Wvh  = (unsigned short*)(ws + 5*NB/4);
    unsigned short* qpre = (unsigned short*)(ws + 3*NB/2);
    unsigned short* kpre = (unsigned short*)(ws + 2*NB);
    unsigned short* vpre = (unsigned short*)(ws + 5*NB/2);
    unsigned short* qh   = (unsigned short*)(ws + 3*NB);
    unsigned short* kh   = (unsigned short*)(ws + 7*NB/2);
    unsigned short* vh   = (unsigned short*)(ws);        // overlays dead xh
    unsigned short* abh  = (unsigned short*)(ws + 3*NB/2); // overlays dead qpre

    // one launch: 4 weights + x as two weight-sized chunks
    f32_to_bf16_multi<<<dim3(WN/1024, 6), 256, 0, stream>>>(
        Wq, Wk, Wv, Wo, x, x + WN,
        Wqh, Wkh, Wvh, Woh, xh, xh + WN);

    const int M = B_ * T_, N = H_, K = H_;
    dim3 gg(N / 128, M / 128);

    gemm_mfma<true><<<gg, 256, 0, stream>>>(xh, Wqh, nullptr, qpre, M, N, K);
    gemm_mfma<true><<<gg, 256, 0, stream>>>(xh, Wkh, nullptr, kpre, M, N, K);
    gemm_mfma<true><<<gg, 256, 0, stream>>>(xh, Wvh, nullptr, vpre, M, N, K);

    rope_convert_qk<<<(B_*T_*NH_*64)/256, 256, 0, stream>>>(qpre, kpre, cosp, sinp, qh, kh);
    transpose_v<<<dim3(T_/64, HD_/64, B_*NH_), 256, 0, stream>>>(vpre, vh);

    attn_mfma<<<dim3(16, B_*NH_), 256, 0, stream>>>(qh, kh, vh, abh);

    gemm_mfma<false><<<gg, 256, 0, stream>>>(abh, Woh, (float*)d_out, nullptr, M, N, K);
}